// Round 1
// baseline (112.371 us; speedup 1.0000x reference)
//
#include <hip/hip_runtime.h>
#include <hip/hip_bf16.h>
#include <math.h>

constexpr int Bn = 1024;   // batch
constexpr int Cn = 1000;   // classes
constexpr int Dn = 256;    // feature dim
constexpr float EPS = 1e-4f;

// ---------------------------------------------------------------------------
// P = F F^T + eps*I.  (F F^T is exactly symmetric -> 0.5*(P+P^T) is a no-op.)
// One block per row i; thread j computes P[i][j] = dot(F_i, F_j).
__global__ __launch_bounds__(256) void p_kernel(const float* __restrict__ F,
                                                float* __restrict__ P) {
    __shared__ float Fi[Dn];
    const int i = blockIdx.x, j = threadIdx.x;
    Fi[j] = F[i * Dn + j];
    __syncthreads();
    float acc = 0.f;
#pragma unroll 8
    for (int k = 0; k < Dn; ++k) acc = fmaf(Fi[k], F[j * Dn + k], acc);
    if (i == j) acc += EPS;
    P[i * Dn + j] = acc;
}

// ---------------------------------------------------------------------------
// XP = X @ P   (X: [N][256] row-major), and xPx[n] = dot(XP[n], X[n]).
// 16 rows per block; thread j owns column j. P row reads are coalesced;
// X reads are block-uniform (compiler emits scalar loads).
__global__ __launch_bounds__(256) void xp_kernel(const float* __restrict__ X,
                                                 const float* __restrict__ P,
                                                 float* __restrict__ XP,   // may be null
                                                 float* __restrict__ xPx,
                                                 int N) {
    const int tid = threadIdx.x;
    const int row0 = blockIdx.x * 16;
    const float* Xr[16];
#pragma unroll
    for (int r = 0; r < 16; ++r) {
        int row = row0 + r;
        if (row > N - 1) row = N - 1;   // clamp; stores are guarded below
        Xr[r] = X + (size_t)row * Dn;
    }
    float acc[16];
#pragma unroll
    for (int r = 0; r < 16; ++r) acc[r] = 0.f;

#pragma unroll 4
    for (int k = 0; k < Dn; ++k) {
        const float pk = P[k * Dn + tid];
#pragma unroll
        for (int r = 0; r < 16; ++r) acc[r] = fmaf(Xr[r][k], pk, acc[r]);
    }

    __shared__ float red[16][4];
    const int lane = tid & 63, wid = tid >> 6;
#pragma unroll
    for (int r = 0; r < 16; ++r) {
        if (XP != nullptr && row0 + r < N)
            XP[(size_t)(row0 + r) * Dn + tid] = acc[r];
        float v = acc[r] * Xr[r][tid];
#pragma unroll
        for (int off = 32; off > 0; off >>= 1) v += __shfl_down(v, off);
        if (lane == 0) red[r][wid] = v;
    }
    __syncthreads();
    if (tid < 16 && row0 + tid < N)
        xPx[row0 + tid] = red[tid][0] + red[tid][1] + red[tid][2] + red[tid][3];
}

// ---------------------------------------------------------------------------
// bias[c] = log_softmax(logits)[c] - 0.5*muPmu[c]
__global__ __launch_bounds__(1024) void bias_kernel(const float* __restrict__ logits,
                                                    const float* __restrict__ muPmu,
                                                    float* __restrict__ bias) {
    __shared__ float red[1024];
    const int tid = threadIdx.x;
    red[tid] = (tid < Cn) ? logits[tid] : -INFINITY;
    __syncthreads();
    for (int s = 512; s > 0; s >>= 1) {
        if (tid < s) red[tid] = fmaxf(red[tid], red[tid + s]);
        __syncthreads();
    }
    const float mx = red[0];
    __syncthreads();
    red[tid] = (tid < Cn) ? expf(logits[tid] - mx) : 0.f;
    __syncthreads();
    for (int s = 512; s > 0; s >>= 1) {
        if (tid < s) red[tid] += red[tid + s];
        __syncthreads();
    }
    const float lse = mx + logf(red[0]);
    if (tid < Cn) bias[tid] = logits[tid] - lse - 0.5f * muPmu[tid];
}

// ---------------------------------------------------------------------------
// out[b][c] = dot(zP[b], mu[c]) + bias[c] - 0.5*zPz[b]
// 64x64 tile per block, 256 threads, 4x4 per thread; K staged in LDS
// transposed with +4 padding (keeps float4 reads 16B-aligned, banks spread).
constexpr int BM = 64, BN = 64, BK = 64;

__global__ __launch_bounds__(256) void gemm_kernel(const float* __restrict__ A,    // zP [Bn][Dn]
                                                   const float* __restrict__ Bm,   // mu [Cn][Dn]
                                                   const float* __restrict__ bias, // [Cn]
                                                   const float* __restrict__ zPz,  // [Bn]
                                                   float* __restrict__ out) {      // [Bn][Cn]
    __shared__ float As[BK][BM + 4];
    __shared__ float Bs[BK][BN + 4];
    const int tid = threadIdx.x;
    const int col0 = blockIdx.x * BN;
    const int row0 = blockIdx.y * BM;
    const int tx = tid & 15, ty = tid >> 4;

    float acc[4][4] = {};

    for (int kt = 0; kt < Dn; kt += BK) {
        // stage A tile (transposed): 64 rows x 64 k, 4 float4 per thread
#pragma unroll
        for (int it = 0; it < 4; ++it) {
            const int l  = tid + it * 256;
            const int r  = l >> 4;          // row in tile
            const int kc = (l & 15) << 2;   // k offset
            const float4 v = *(const float4*)&A[(size_t)(row0 + r) * Dn + kt + kc];
            As[kc + 0][r] = v.x; As[kc + 1][r] = v.y;
            As[kc + 2][r] = v.z; As[kc + 3][r] = v.w;
        }
        // stage B tile (transposed), guard cols >= Cn
#pragma unroll
        for (int it = 0; it < 4; ++it) {
            const int l  = tid + it * 256;
            const int r  = l >> 4;
            const int kc = (l & 15) << 2;
            const int gc = col0 + r;
            float4 v = make_float4(0.f, 0.f, 0.f, 0.f);
            if (gc < Cn) v = *(const float4*)&Bm[(size_t)gc * Dn + kt + kc];
            Bs[kc + 0][r] = v.x; Bs[kc + 1][r] = v.y;
            Bs[kc + 2][r] = v.z; Bs[kc + 3][r] = v.w;
        }
        __syncthreads();

#pragma unroll
        for (int k = 0; k < BK; ++k) {
            const float4 a = *(const float4*)&As[k][ty << 2];
            const float4 b = *(const float4*)&Bs[k][tx << 2];
            acc[0][0] = fmaf(a.x, b.x, acc[0][0]);
            acc[0][1] = fmaf(a.x, b.y, acc[0][1]);
            acc[0][2] = fmaf(a.x, b.z, acc[0][2]);
            acc[0][3] = fmaf(a.x, b.w, acc[0][3]);
            acc[1][0] = fmaf(a.y, b.x, acc[1][0]);
            acc[1][1] = fmaf(a.y, b.y, acc[1][1]);
            acc[1][2] = fmaf(a.y, b.z, acc[1][2]);
            acc[1][3] = fmaf(a.y, b.w, acc[1][3]);
            acc[2][0] = fmaf(a.z, b.x, acc[2][0]);
            acc[2][1] = fmaf(a.z, b.y, acc[2][1]);
            acc[2][2] = fmaf(a.z, b.z, acc[2][2]);
            acc[2][3] = fmaf(a.z, b.w, acc[2][3]);
            acc[3][0] = fmaf(a.w, b.x, acc[3][0]);
            acc[3][1] = fmaf(a.w, b.y, acc[3][1]);
            acc[3][2] = fmaf(a.w, b.z, acc[3][2]);
            acc[3][3] = fmaf(a.w, b.w, acc[3][3]);
        }
        __syncthreads();
    }

    // epilogue
    const int m0 = ty << 2, n0 = tx << 2;
#pragma unroll
    for (int i = 0; i < 4; ++i) {
        const int gr = row0 + m0 + i;
        const float zb = -0.5f * zPz[gr];
        const int gc = col0 + n0;
        if (gc + 3 < Cn) {
            float4 o;
            o.x = acc[i][0] + bias[gc + 0] + zb;
            o.y = acc[i][1] + bias[gc + 1] + zb;
            o.z = acc[i][2] + bias[gc + 2] + zb;
            o.w = acc[i][3] + bias[gc + 3] + zb;
            *(float4*)&out[(size_t)gr * Cn + gc] = o;
        } else {
#pragma unroll
            for (int j = 0; j < 4; ++j)
                if (gc + j < Cn)
                    out[(size_t)gr * Cn + gc + j] = acc[i][j] + bias[gc + j] + zb;
        }
    }
}

// ---------------------------------------------------------------------------
extern "C" void kernel_launch(void* const* d_in, const int* in_sizes, int n_in,
                              void* d_out, int out_size, void* d_ws, size_t ws_size,
                              hipStream_t stream) {
    const float* z      = (const float*)d_in[0];   // [1024][256]
    const float* mu     = (const float*)d_in[1];   // [1000][256]
    const float* logits = (const float*)d_in[2];   // [1000]
    const float* F      = (const float*)d_in[3];   // [256][256]
    float* out = (float*)d_out;                    // [1024][1000]

    char* ws = (char*)d_ws;
    float* P     = (float*)(ws);                                   // 256 KB
    float* zP    = (float*)(ws + 256 * 256 * 4);                   // 1 MB
    float* zPz   = (float*)(ws + 256 * 256 * 4 + 1024 * 256 * 4);  // 4 KB
    float* muPmu = zPz + 1024;                                     // 4 KB
    float* bias  = muPmu + 1024;                                   // 4 KB

    p_kernel<<<dim3(Dn), dim3(256), 0, stream>>>(F, P);
    xp_kernel<<<dim3(Bn / 16), dim3(256), 0, stream>>>(z, P, zP, zPz, Bn);
    xp_kernel<<<dim3((Cn + 15) / 16), dim3(256), 0, stream>>>(mu, P, nullptr, muPmu, Cn);
    bias_kernel<<<dim3(1), dim3(1024), 0, stream>>>(logits, muPmu, bias);
    gemm_kernel<<<dim3((Cn + BN - 1) / BN, Bn / BM), dim3(256), 0, stream>>>(zP, mu, bias, zPz, out);
}

// Round 2
// 65.480 us; speedup vs baseline: 1.7161x; 1.7161x over previous
//
#include <hip/hip_runtime.h>
#include <hip/hip_bf16.h>
#include <math.h>

constexpr int Bn = 1024;   // batch
constexpr int Cn = 1000;   // classes
constexpr int Dn = 256;    // feature dim
constexpr float EPS = 1e-4f;

constexpr int BM = 64, BN = 64, BK = 64;

// ---------------------------------------------------------------------------
// Shared 16-FMA micro-kernel on a 4x4 register tile.
#define MICRO_FMA(acc, a, b)                         \
    do {                                             \
        acc[0][0] = fmaf(a.x, b.x, acc[0][0]);       \
        acc[0][1] = fmaf(a.x, b.y, acc[0][1]);       \
        acc[0][2] = fmaf(a.x, b.z, acc[0][2]);       \
        acc[0][3] = fmaf(a.x, b.w, acc[0][3]);       \
        acc[1][0] = fmaf(a.y, b.x, acc[1][0]);       \
        acc[1][1] = fmaf(a.y, b.y, acc[1][1]);       \
        acc[1][2] = fmaf(a.y, b.z, acc[1][2]);       \
        acc[1][3] = fmaf(a.y, b.w, acc[1][3]);       \
        acc[2][0] = fmaf(a.z, b.x, acc[2][0]);       \
        acc[2][1] = fmaf(a.z, b.y, acc[2][1]);       \
        acc[2][2] = fmaf(a.z, b.z, acc[2][2]);       \
        acc[2][3] = fmaf(a.z, b.w, acc[2][3]);       \
        acc[3][0] = fmaf(a.w, b.x, acc[3][0]);       \
        acc[3][1] = fmaf(a.w, b.y, acc[3][1]);       \
        acc[3][2] = fmaf(a.w, b.z, acc[3][2]);       \
        acc[3][3] = fmaf(a.w, b.w, acc[3][3]);       \
    } while (0)

// ---------------------------------------------------------------------------
// P = F F^T + eps*I   (NT gemm, M=N=K=256; F F^T is exactly symmetric so the
// reference's 0.5*(P+P^T) is a no-op).
__global__ __launch_bounds__(256) void p_gemm_kernel(const float* __restrict__ F,
                                                     float* __restrict__ P) {
    __shared__ float As[BK][BM + 4];
    __shared__ float Bs[BK][BN + 4];
    const int tid = threadIdx.x;
    const int col0 = blockIdx.x * BN;
    const int row0 = blockIdx.y * BM;
    const int tx = tid & 15, ty = tid >> 4;

    float acc[4][4] = {};

    for (int kt = 0; kt < Dn; kt += BK) {
#pragma unroll
        for (int it = 0; it < 4; ++it) {
            const int l  = tid + it * 256;
            const int r  = l >> 4;
            const int kc = (l & 15) << 2;
            const float4 va = *(const float4*)&F[(size_t)(row0 + r) * Dn + kt + kc];
            As[kc + 0][r] = va.x; As[kc + 1][r] = va.y;
            As[kc + 2][r] = va.z; As[kc + 3][r] = va.w;
            const float4 vb = *(const float4*)&F[(size_t)(col0 + r) * Dn + kt + kc];
            Bs[kc + 0][r] = vb.x; Bs[kc + 1][r] = vb.y;
            Bs[kc + 2][r] = vb.z; Bs[kc + 3][r] = vb.w;
        }
        __syncthreads();
#pragma unroll
        for (int k = 0; k < BK; ++k) {
            const float4 a = *(const float4*)&As[k][ty << 2];
            const float4 b = *(const float4*)&Bs[k][tx << 2];
            MICRO_FMA(acc, a, b);
        }
        __syncthreads();
    }

    const int m0 = ty << 2, n0 = tx << 2;
#pragma unroll
    for (int i = 0; i < 4; ++i) {
        const int gr = row0 + m0 + i;
        float4 o;
        o.x = acc[i][0]; o.y = acc[i][1]; o.z = acc[i][2]; o.w = acc[i][3];
        const int gc = col0 + n0;
        if (gr == gc + 0) o.x += EPS;
        if (gr == gc + 1) o.y += EPS;
        if (gr == gc + 2) o.z += EPS;
        if (gr == gc + 3) o.w += EPS;
        *(float4*)&P[(size_t)gr * Dn + gc] = o;
    }
}

// ---------------------------------------------------------------------------
// XP = X @ P  (NN gemm: X [M][256] row-major, P [256][256] row-major).
__global__ __launch_bounds__(256) void xp_gemm_kernel(const float* __restrict__ X,
                                                      const float* __restrict__ P,
                                                      float* __restrict__ XP,
                                                      int M) {
    __shared__ float As[BK][BM + 4];
    __shared__ float Bs[BK][BN + 4];
    const int tid = threadIdx.x;
    const int col0 = blockIdx.x * BN;
    const int row0 = blockIdx.y * BM;
    const int tx = tid & 15, ty = tid >> 4;

    float acc[4][4] = {};

    for (int kt = 0; kt < Dn; kt += BK) {
#pragma unroll
        for (int it = 0; it < 4; ++it) {
            const int l  = tid + it * 256;
            const int r  = l >> 4;          // row (A) / k (B) within tile
            const int kc = (l & 15) << 2;
            int gr = row0 + r;
            if (gr > M - 1) gr = M - 1;     // clamp; stores guarded
            const float4 va = *(const float4*)&X[(size_t)gr * Dn + kt + kc];
            As[kc + 0][r] = va.x; As[kc + 1][r] = va.y;
            As[kc + 2][r] = va.z; As[kc + 3][r] = va.w;
            // B tile: Bs[k][n] = P[kt + r][col0 + kc.*] (direct, no transpose)
            *(float4*)&Bs[r][kc] = *(const float4*)&P[(size_t)(kt + r) * Dn + col0 + kc];
        }
        __syncthreads();
#pragma unroll
        for (int k = 0; k < BK; ++k) {
            const float4 a = *(const float4*)&As[k][ty << 2];
            const float4 b = *(const float4*)&Bs[k][tx << 2];
            MICRO_FMA(acc, a, b);
        }
        __syncthreads();
    }

    const int m0 = ty << 2, n0 = tx << 2;
#pragma unroll
    for (int i = 0; i < 4; ++i) {
        const int gr = row0 + m0 + i;
        if (gr < M) {
            float4 o;
            o.x = acc[i][0]; o.y = acc[i][1]; o.z = acc[i][2]; o.w = acc[i][3];
            *(float4*)&XP[(size_t)gr * Dn + col0 + n0] = o;
        }
    }
}

// ---------------------------------------------------------------------------
// Fused row-dots: o1[r] = dot(A1[r], B1[r]) for r<n1; same for set 2.
// One wave per row, float4 loads (64 lanes x 4 = 256 = Dn).
__global__ __launch_bounds__(256) void rowdot_kernel(const float* __restrict__ A1,
                                                     const float* __restrict__ B1,
                                                     float* __restrict__ o1, int n1,
                                                     const float* __restrict__ A2,
                                                     const float* __restrict__ B2,
                                                     float* __restrict__ o2, int n2) {
    const int nb1 = (n1 + 3) / 4;
    const int blk = blockIdx.x;
    const float* A; const float* Bx; float* o; int row;
    if (blk < nb1) {
        A = A1; Bx = B1; o = o1;
        row = blk * 4 + (threadIdx.x >> 6);
        if (row >= n1) return;
    } else {
        A = A2; Bx = B2; o = o2;
        row = (blk - nb1) * 4 + (threadIdx.x >> 6);
        if (row >= n2) return;
    }
    const int lane = threadIdx.x & 63;
    const float4 a = *(const float4*)&A[(size_t)row * Dn + (lane << 2)];
    const float4 b = *(const float4*)&Bx[(size_t)row * Dn + (lane << 2)];
    float v = a.x * b.x + a.y * b.y + a.z * b.z + a.w * b.w;
#pragma unroll
    for (int off = 32; off > 0; off >>= 1) v += __shfl_down(v, off);
    if (lane == 0) o[row] = v;
}

// ---------------------------------------------------------------------------
// bias[c] = log_softmax(logits)[c] - 0.5*muPmu[c]
__global__ __launch_bounds__(1024) void bias_kernel(const float* __restrict__ logits,
                                                    const float* __restrict__ muPmu,
                                                    float* __restrict__ bias) {
    __shared__ float red[1024];
    const int tid = threadIdx.x;
    red[tid] = (tid < Cn) ? logits[tid] : -INFINITY;
    __syncthreads();
    for (int s = 512; s > 0; s >>= 1) {
        if (tid < s) red[tid] = fmaxf(red[tid], red[tid + s]);
        __syncthreads();
    }
    const float mx = red[0];
    __syncthreads();
    red[tid] = (tid < Cn) ? expf(logits[tid] - mx) : 0.f;
    __syncthreads();
    for (int s = 512; s > 0; s >>= 1) {
        if (tid < s) red[tid] += red[tid + s];
        __syncthreads();
    }
    const float lse = mx + logf(red[0]);
    if (tid < Cn) bias[tid] = logits[tid] - lse - 0.5f * muPmu[tid];
}

// ---------------------------------------------------------------------------
// out[b][c] = dot(zP[b], mu[c]) + bias[c] - 0.5*zPz[b]   (NT gemm)
__global__ __launch_bounds__(256) void gemm_kernel(const float* __restrict__ A,    // zP [Bn][Dn]
                                                   const float* __restrict__ Bm,   // mu [Cn][Dn]
                                                   const float* __restrict__ bias, // [Cn]
                                                   const float* __restrict__ zPz,  // [Bn]
                                                   float* __restrict__ out) {      // [Bn][Cn]
    __shared__ float As[BK][BM + 4];
    __shared__ float Bs[BK][BN + 4];
    const int tid = threadIdx.x;
    const int col0 = blockIdx.x * BN;
    const int row0 = blockIdx.y * BM;
    const int tx = tid & 15, ty = tid >> 4;

    float acc[4][4] = {};

    for (int kt = 0; kt < Dn; kt += BK) {
#pragma unroll
        for (int it = 0; it < 4; ++it) {
            const int l  = tid + it * 256;
            const int r  = l >> 4;
            const int kc = (l & 15) << 2;
            const float4 va = *(const float4*)&A[(size_t)(row0 + r) * Dn + kt + kc];
            As[kc + 0][r] = va.x; As[kc + 1][r] = va.y;
            As[kc + 2][r] = va.z; As[kc + 3][r] = va.w;
            const int gc = col0 + r;
            float4 vb = make_float4(0.f, 0.f, 0.f, 0.f);
            if (gc < Cn) vb = *(const float4*)&Bm[(size_t)gc * Dn + kt + kc];
            Bs[kc + 0][r] = vb.x; Bs[kc + 1][r] = vb.y;
            Bs[kc + 2][r] = vb.z; Bs[kc + 3][r] = vb.w;
        }
        __syncthreads();
#pragma unroll
        for (int k = 0; k < BK; ++k) {
            const float4 a = *(const float4*)&As[k][ty << 2];
            const float4 b = *(const float4*)&Bs[k][tx << 2];
            MICRO_FMA(acc, a, b);
        }
        __syncthreads();
    }

    const int m0 = ty << 2, n0 = tx << 2;
#pragma unroll
    for (int i = 0; i < 4; ++i) {
        const int gr = row0 + m0 + i;
        const float zb = -0.5f * zPz[gr];
        const int gc = col0 + n0;
        if (gc + 3 < Cn) {
            float4 o;
            o.x = acc[i][0] + bias[gc + 0] + zb;
            o.y = acc[i][1] + bias[gc + 1] + zb;
            o.z = acc[i][2] + bias[gc + 2] + zb;
            o.w = acc[i][3] + bias[gc + 3] + zb;
            *(float4*)&out[(size_t)gr * Cn + gc] = o;
        } else {
#pragma unroll
            for (int j = 0; j < 4; ++j)
                if (gc + j < Cn)
                    out[(size_t)gr * Cn + gc + j] = acc[i][j] + bias[gc + j] + zb;
        }
    }
}

// ---------------------------------------------------------------------------
extern "C" void kernel_launch(void* const* d_in, const int* in_sizes, int n_in,
                              void* d_out, int out_size, void* d_ws, size_t ws_size,
                              hipStream_t stream) {
    const float* z      = (const float*)d_in[0];   // [1024][256]
    const float* mu     = (const float*)d_in[1];   // [1000][256]
    const float* logits = (const float*)d_in[2];   // [1000]
    const float* F      = (const float*)d_in[3];   // [256][256]
    float* out = (float*)d_out;                    // [1024][1000]

    char* ws = (char*)d_ws;
    float* P     = (float*)(ws);                                   // 256 KB
    float* zP    = (float*)(ws + 256 * 256 * 4);                   // 1 MB
    float* zPz   = (float*)(ws + 256 * 256 * 4 + 1024 * 256 * 4);  // 4 KB
    float* muPmu = zPz + 1024;                                     // 4 KB
    float* bias  = muPmu + 1024;                                   // 4 KB
    // muP is only needed to form muPmu; stage it in d_out (fully overwritten
    // by the final gemm afterwards). 1000*256 floats = 1 MB < 4 MB out.
    float* muP   = out;

    p_gemm_kernel<<<dim3(4, 4), dim3(256), 0, stream>>>(F, P);
    xp_gemm_kernel<<<dim3(4, Bn / BM), dim3(256), 0, stream>>>(z, P, zP, Bn);
    xp_gemm_kernel<<<dim3(4, (Cn + BM - 1) / BM), dim3(256), 0, stream>>>(mu, P, muP, Cn);
    rowdot_kernel<<<dim3(Bn / 4 + (Cn + 3) / 4), dim3(256), 0, stream>>>(
        zP, z, zPz, Bn, muP, mu, muPmu, Cn);
    bias_kernel<<<dim3(1), dim3(1024), 0, stream>>>(logits, muPmu, bias);
    gemm_kernel<<<dim3((Cn + BN - 1) / BN, Bn / BM), dim3(256), 0, stream>>>(zP, mu, bias, zPz, out);
}

// Round 3
// 35.654 us; speedup vs baseline: 3.1517x; 1.8365x over previous
//
#include <hip/hip_runtime.h>
#include <hip/hip_bf16.h>
#include <math.h>

constexpr int Bn = 1024;   // batch
constexpr int Cn = 1000;   // classes
constexpr int Dn = 256;    // feature dim
constexpr float EPS = 1e-4f;

constexpr int BM = 64, BN = 64, BK = 64;

// 16-FMA micro-kernel on a 4x4 register tile.
#define MICRO_FMA(acc, a, b)                         \
    do {                                             \
        acc[0][0] = fmaf(a.x, b.x, acc[0][0]);       \
        acc[0][1] = fmaf(a.x, b.y, acc[0][1]);       \
        acc[0][2] = fmaf(a.x, b.z, acc[0][2]);       \
        acc[0][3] = fmaf(a.x, b.w, acc[0][3]);       \
        acc[1][0] = fmaf(a.y, b.x, acc[1][0]);       \
        acc[1][1] = fmaf(a.y, b.y, acc[1][1]);       \
        acc[1][2] = fmaf(a.y, b.z, acc[1][2]);       \
        acc[1][3] = fmaf(a.y, b.w, acc[1][3]);       \
        acc[2][0] = fmaf(a.z, b.x, acc[2][0]);       \
        acc[2][1] = fmaf(a.z, b.y, acc[2][1]);       \
        acc[2][2] = fmaf(a.z, b.z, acc[2][2]);       \
        acc[2][3] = fmaf(a.z, b.w, acc[2][3]);       \
        acc[3][0] = fmaf(a.w, b.x, acc[3][0]);       \
        acc[3][1] = fmaf(a.w, b.y, acc[3][1]);       \
        acc[3][2] = fmaf(a.w, b.z, acc[3][2]);       \
        acc[3][3] = fmaf(a.w, b.w, acc[3][3]);       \
    } while (0)

// ---------------------------------------------------------------------------
// K1: bid 0..63   -> Y = z @ F   (+ eps*||z_row||^2 when col0==0)
//     bid 64..127 -> U = mu @ F  (rows >= Cn stored as 0; + eps*||mu_row||^2)
//     bid 128     -> lse = logsumexp(logits)
__global__ __launch_bounds__(256) void prep_kernel(const float* __restrict__ z,
                                                   const float* __restrict__ mu,
                                                   const float* __restrict__ logits,
                                                   const float* __restrict__ F,
                                                   float* __restrict__ Y,
                                                   float* __restrict__ U,
                                                   float* __restrict__ epsn_z,
                                                   float* __restrict__ epsn_mu,
                                                   float* __restrict__ lse_out) {
    __shared__ float As[BK][BM + 4];
    __shared__ float Bs[BK][BN + 4];
    __shared__ float red2[64][4];
    const int bid = blockIdx.x;
    const int tid = threadIdx.x;

    if (bid == 128) {   // logsumexp over logits[0..Cn)
        __shared__ float red[256];
        float mx = -INFINITY;
        for (int i = tid; i < Cn; i += 256) mx = fmaxf(mx, logits[i]);
        red[tid] = mx; __syncthreads();
        for (int s = 128; s > 0; s >>= 1) {
            if (tid < s) red[tid] = fmaxf(red[tid], red[tid + s]);
            __syncthreads();
        }
        mx = red[0]; __syncthreads();
        float sm = 0.f;
        for (int i = tid; i < Cn; i += 256) sm += expf(logits[i] - mx);
        red[tid] = sm; __syncthreads();
        for (int s = 128; s > 0; s >>= 1) {
            if (tid < s) red[tid] += red[tid + s];
            __syncthreads();
        }
        if (tid == 0) *lse_out = mx + logf(red[0]);
        return;
    }

    const bool isMu = bid >= 64;
    const int  b    = isMu ? bid - 64 : bid;
    const float* X  = isMu ? mu : z;
    float* XF       = isMu ? U : Y;
    float* epsn     = isMu ? epsn_mu : epsn_z;
    const int M     = isMu ? Cn : Bn;
    const int row0  = (b >> 2) * BM;
    const int col0  = (b & 3) * BN;
    const int tx = tid & 15, ty = tid >> 4;

    float acc[4][4] = {};

    for (int kt = 0; kt < Dn; kt += BK) {
#pragma unroll
        for (int it = 0; it < 4; ++it) {
            const int l  = tid + it * 256;
            const int r  = l >> 4;
            const int kc = (l & 15) << 2;
            int gr = row0 + r;
            if (gr > M - 1) gr = M - 1;
            const float4 va = *(const float4*)&X[(size_t)gr * Dn + kt + kc];
            As[kc + 0][r] = va.x; As[kc + 1][r] = va.y;
            As[kc + 2][r] = va.z; As[kc + 3][r] = va.w;
            *(float4*)&Bs[r][kc] = *(const float4*)&F[(size_t)(kt + r) * Dn + col0 + kc];
        }
        __syncthreads();
#pragma unroll
        for (int k = 0; k < BK; ++k) {
            const float4 a = *(const float4*)&As[k][ty << 2];
            const float4 b4 = *(const float4*)&Bs[k][tx << 2];
            MICRO_FMA(acc, a, b4);
        }
        __syncthreads();
    }

    const int m0 = ty << 2, n0 = tx << 2;
#pragma unroll
    for (int i = 0; i < 4; ++i) {
        const int gr = row0 + m0 + i;       // always < 1024 (padded alloc)
        float4 o = make_float4(0.f, 0.f, 0.f, 0.f);
        if (gr < M) { o.x = acc[i][0]; o.y = acc[i][1]; o.z = acc[i][2]; o.w = acc[i][3]; }
        *(float4*)&XF[(size_t)gr * Dn + col0 + n0] = o;
    }

    if (col0 == 0) {   // eps * ||X_row||^2 for this block's 64 rows
        const int r = tid >> 2, q = tid & 3;
        int gr = row0 + r;
        if (gr > M - 1) gr = M - 1;
        const float4* px = (const float4*)&X[(size_t)gr * Dn + q * 64];
        float s = 0.f;
#pragma unroll
        for (int i = 0; i < 16; ++i) {
            const float4 v = px[i];
            s += v.x * v.x + v.y * v.y + v.z * v.z + v.w * v.w;
        }
        red2[r][q] = s;
        __syncthreads();
        if (tid < 64)
            epsn[row0 + tid] = (row0 + tid < M)
                ? EPS * (red2[tid][0] + red2[tid][1] + red2[tid][2] + red2[tid][3])
                : 0.f;
    }
}

// ---------------------------------------------------------------------------
// K2: out[b][c] = Y_b . U_c + (logits[c] - lse - 0.5*(||U_c||^2 + epsn_mu[c]))
//                 - 0.5*(||Y_b||^2 + epsn_z[b])
// Row/col norms computed in-block from the staged LDS tiles.
__global__ __launch_bounds__(256) void main_gemm_kernel(const float* __restrict__ A,   // Y [1024][256]
                                                        const float* __restrict__ Bm,  // U [1024][256], rows>=Cn zero
                                                        const float* __restrict__ logits,
                                                        const float* __restrict__ epsn_z,
                                                        const float* __restrict__ epsn_mu,
                                                        const float* __restrict__ lse_p,
                                                        float* __restrict__ out) {     // [Bn][Cn]
    __shared__ float As[BK][BM + 4];
    __shared__ float Bs[BK][BN + 4];
    __shared__ float rpart[4][64], cpart[4][64];
    __shared__ float rnorm[BM], cnorm[BN];
    const int tid = threadIdx.x;
    const int col0 = blockIdx.x * BN;
    const int row0 = blockIdx.y * BM;
    const int tx = tid & 15, ty = tid >> 4;
    const int rr = tid & 63, kg = tid >> 6;

    float acc[4][4] = {};
    float rn = 0.f, cn = 0.f;

    for (int kt = 0; kt < Dn; kt += BK) {
#pragma unroll
        for (int it = 0; it < 4; ++it) {
            const int l  = tid + it * 256;
            const int r  = l >> 4;
            const int kc = (l & 15) << 2;
            const float4 va = *(const float4*)&A[(size_t)(row0 + r) * Dn + kt + kc];
            As[kc + 0][r] = va.x; As[kc + 1][r] = va.y;
            As[kc + 2][r] = va.z; As[kc + 3][r] = va.w;
            const float4 vb = *(const float4*)&Bm[(size_t)(col0 + r) * Dn + kt + kc];
            Bs[kc + 0][r] = vb.x; Bs[kc + 1][r] = vb.y;
            Bs[kc + 2][r] = vb.z; Bs[kc + 3][r] = vb.w;
        }
        __syncthreads();
        // norm partials from staged tiles (each thread: 16 k for one row/col)
#pragma unroll
        for (int k = kg * 16; k < kg * 16 + 16; ++k) {
            const float a = As[k][rr];
            rn = fmaf(a, a, rn);
            const float bb = Bs[k][rr];
            cn = fmaf(bb, bb, cn);
        }
#pragma unroll
        for (int k = 0; k < BK; ++k) {
            const float4 a  = *(const float4*)&As[k][ty << 2];
            const float4 b4 = *(const float4*)&Bs[k][tx << 2];
            MICRO_FMA(acc, a, b4);
        }
        __syncthreads();
    }

    rpart[kg][rr] = rn;
    cpart[kg][rr] = cn;
    __syncthreads();
    if (tid < 64)
        rnorm[tid] = rpart[0][tid] + rpart[1][tid] + rpart[2][tid] + rpart[3][tid];
    else if (tid < 128) {
        const int c = tid - 64;
        cnorm[c] = cpart[0][c] + cpart[1][c] + cpart[2][c] + cpart[3][c];
    }
    __syncthreads();

    const float lse = *lse_p;
    const int m0 = ty << 2, n0 = tx << 2;
    float bias[4];
#pragma unroll
    for (int j = 0; j < 4; ++j) {
        const int gc = col0 + n0 + j;
        bias[j] = (gc < Cn) ? logits[gc] - lse - 0.5f * (cnorm[n0 + j] + epsn_mu[gc]) : 0.f;
    }
#pragma unroll
    for (int i = 0; i < 4; ++i) {
        const int gr = row0 + m0 + i;
        const float zb = -0.5f * (rnorm[m0 + i] + epsn_z[gr]);
        const int gc = col0 + n0;
        if (gc + 3 < Cn) {
            float4 o;
            o.x = acc[i][0] + bias[0] + zb;
            o.y = acc[i][1] + bias[1] + zb;
            o.z = acc[i][2] + bias[2] + zb;
            o.w = acc[i][3] + bias[3] + zb;
            *(float4*)&out[(size_t)gr * Cn + gc] = o;
        } else {
#pragma unroll
            for (int j = 0; j < 4; ++j)
                if (gc + j < Cn)
                    out[(size_t)gr * Cn + gc + j] = acc[i][j] + bias[j] + zb;
        }
    }
}

// ---------------------------------------------------------------------------
extern "C" void kernel_launch(void* const* d_in, const int* in_sizes, int n_in,
                              void* d_out, int out_size, void* d_ws, size_t ws_size,
                              hipStream_t stream) {
    const float* z      = (const float*)d_in[0];   // [1024][256]
    const float* mu     = (const float*)d_in[1];   // [1000][256]
    const float* logits = (const float*)d_in[2];   // [1000]
    const float* F      = (const float*)d_in[3];   // [256][256]
    float* out = (float*)d_out;                    // [1024][1000]

    char* ws = (char*)d_ws;
    float* Y       = (float*)(ws);                              // 1 MB  [1024][256]
    float* U       = (float*)(ws + (1 << 20));                  // 1 MB  [1024][256]
    float* epsn_z  = (float*)(ws + (2 << 20));                  // 4 KB
    float* epsn_mu = epsn_z + 1024;                             // 4 KB
    float* lse     = epsn_mu + 1024;                            // 4 B

    prep_kernel<<<dim3(129), dim3(256), 0, stream>>>(z, mu, logits, F, Y, U,
                                                     epsn_z, epsn_mu, lse);
    main_gemm_kernel<<<dim3(16, 16), dim3(256), 0, stream>>>(Y, U, logits,
                                                             epsn_z, epsn_mu, lse, out);
}

// Round 4
// 22.598 us; speedup vs baseline: 4.9725x; 1.5777x over previous
//
#include <hip/hip_runtime.h>
#include <hip/hip_bf16.h>
#include <math.h>

constexpr int Bn = 1024;   // batch
constexpr int Cn = 1000;   // classes
constexpr int Dn = 256;    // feature dim
constexpr float EPS = 1e-4f;

typedef __attribute__((ext_vector_type(8))) short bf16x8;
typedef __attribute__((ext_vector_type(4))) float f32x4;

// f32 -> bf16 round-to-nearest-even
static __device__ __forceinline__ unsigned short f2bf(float x) {
    union { float f; unsigned u; } v; v.f = x;
    unsigned r = (v.u + 0x7fffu + ((v.u >> 16) & 1u)) >> 16;
    return (unsigned short)r;
}

// ---------------------------------------------------------------------------
// Prep (f32 FMA, 64 rows x 32 cols per block, 4x2 micro-tile):
//   bid 0..127   : Y-tiles  (Y = z @ F), write Yb (bf16) + rn_part + epsn_z
//   bid 128..255 : U-tiles  (U = mu @ F, rows clamped), Ub + cn_part + epsn_mu
//   bid 256      : lse = logsumexp(logits)
// Norm partials: npart[row*8 + colTile] = sum of Y[row][colTile*32 .. +31]^2 (f32).
__global__ __launch_bounds__(256) void prep_kernel(const float* __restrict__ z,
                                                   const float* __restrict__ mu,
                                                   const float* __restrict__ logits,
                                                   const float* __restrict__ F,
                                                   unsigned short* __restrict__ Yb,
                                                   unsigned short* __restrict__ Ub,
                                                   float* __restrict__ rn_part,
                                                   float* __restrict__ cn_part,
                                                   float* __restrict__ epsn_z,
                                                   float* __restrict__ epsn_mu,
                                                   float* __restrict__ lse_out) {
    __shared__ float As[64][68];   // [k][row], +4 pad keeps float4 reads 16B-aligned
    __shared__ float Bs[64][36];   // [k][col]
    __shared__ float red[64][17];
    const int bid = blockIdx.x, tid = threadIdx.x;

    if (bid == 256) {   // logsumexp over logits[0..Cn)
        float* rl = &red[0][0];
        float mx = -INFINITY;
        for (int i = tid; i < Cn; i += 256) mx = fmaxf(mx, logits[i]);
        rl[tid] = mx; __syncthreads();
        for (int s = 128; s > 0; s >>= 1) {
            if (tid < s) rl[tid] = fmaxf(rl[tid], rl[tid + s]);
            __syncthreads();
        }
        mx = rl[0]; __syncthreads();
        float sm = 0.f;
        for (int i = tid; i < Cn; i += 256) sm += expf(logits[i] - mx);
        rl[tid] = sm; __syncthreads();
        for (int s = 128; s > 0; s >>= 1) {
            if (tid < s) rl[tid] += rl[tid + s];
            __syncthreads();
        }
        if (tid == 0) *lse_out = mx + logf(rl[0]);
        return;
    }

    const bool isMu = bid >= 128;
    const int  b    = isMu ? bid - 128 : bid;
    const float* X  = isMu ? mu : z;
    unsigned short* XB = isMu ? Ub : Yb;
    float* npart    = isMu ? cn_part : rn_part;
    float* epsn     = isMu ? epsn_mu : epsn_z;
    const int M     = isMu ? Cn : Bn;
    const int row0  = (b >> 3) * 64;
    const int ct    = b & 7;
    const int col0  = ct * 32;
    const int tx = tid & 15, ty = tid >> 4;

    float acc[4][2] = {};

    for (int kt = 0; kt < Dn; kt += 64) {
        // stage A transposed: As[k][row]
#pragma unroll
        for (int it = 0; it < 4; ++it) {
            const int l  = tid + it * 256;
            const int r  = l >> 4;
            const int kc = (l & 15) << 2;
            int gr = row0 + r;
            if (gr > M - 1) gr = M - 1;
            const float4 va = *(const float4*)&X[(size_t)gr * Dn + kt + kc];
            As[kc + 0][r] = va.x; As[kc + 1][r] = va.y;
            As[kc + 2][r] = va.z; As[kc + 3][r] = va.w;
        }
        // stage B direct: Bs[k][col]
#pragma unroll
        for (int it = 0; it < 2; ++it) {
            const int l  = tid + it * 256;
            const int r  = l >> 3;
            const int kc = (l & 7) << 2;
            *(float4*)&Bs[r][kc] = *(const float4*)&F[(size_t)(kt + r) * Dn + col0 + kc];
        }
        __syncthreads();
#pragma unroll
        for (int k = 0; k < 64; ++k) {
            const float4 a  = *(const float4*)&As[k][ty << 2];
            const float2 bb = *(const float2*)&Bs[k][tx << 1];
            acc[0][0] = fmaf(a.x, bb.x, acc[0][0]);
            acc[0][1] = fmaf(a.x, bb.y, acc[0][1]);
            acc[1][0] = fmaf(a.y, bb.x, acc[1][0]);
            acc[1][1] = fmaf(a.y, bb.y, acc[1][1]);
            acc[2][0] = fmaf(a.z, bb.x, acc[2][0]);
            acc[2][1] = fmaf(a.z, bb.y, acc[2][1]);
            acc[3][0] = fmaf(a.w, bb.x, acc[3][0]);
            acc[3][1] = fmaf(a.w, bb.y, acc[3][1]);
        }
        __syncthreads();
    }

    // bf16 store (rows >= M hold clamped-row data: finite, never read as valid output)
#pragma unroll
    for (int i = 0; i < 4; ++i) {
        const int gr = row0 + (ty << 2) + i;   // always < 1024 (padded alloc)
        ushort2 s;
        s.x = f2bf(acc[i][0]);
        s.y = f2bf(acc[i][1]);
        *(ushort2*)&XB[(size_t)gr * Dn + col0 + (tx << 1)] = s;
    }

    // f32 norm partials over this col-tile
#pragma unroll
    for (int i = 0; i < 4; ++i)
        red[(ty << 2) + i][tx] = acc[i][0] * acc[i][0] + acc[i][1] * acc[i][1];
    __syncthreads();
    if (tid < 64) {
        float s = 0.f;
#pragma unroll
        for (int x = 0; x < 16; ++x) s += red[tid][x];
        npart[(size_t)(row0 + tid) * 8 + ct] = s;
    }

    if (ct == 0) {   // eps * ||X_row||^2
        const int r = tid >> 2, q = tid & 3;
        int gr = row0 + r;
        if (gr > M - 1) gr = M - 1;
        const float4* px = (const float4*)&X[(size_t)gr * Dn + (q << 6)];
        float s = 0.f;
#pragma unroll
        for (int i = 0; i < 16; ++i) {
            const float4 v = px[i];
            s += v.x * v.x + v.y * v.y + v.z * v.z + v.w * v.w;
        }
        __syncthreads();
        red[r][q] = s;
        __syncthreads();
        if (tid < 64)
            epsn[row0 + tid] = (row0 + tid < M)
                ? EPS * (red[tid][0] + red[tid][1] + red[tid][2] + red[tid][3])
                : 0.f;
    }
}

// ---------------------------------------------------------------------------
// Main: out[b][c] = mfma_bf16(Y_b . U_c) + rowbias[b] + colbias[c]
// 64x64 tile/block, 4 waves of 32x32, fragments loaded straight from global
// (Y/U are L2-resident, 1 MB total). No LDS staging.
__global__ __launch_bounds__(256) void main_kernel(const unsigned short* __restrict__ Yb,
                                                   const unsigned short* __restrict__ Ub,
                                                   const float* __restrict__ rn_part,
                                                   const float* __restrict__ cn_part,
                                                   const float* __restrict__ epsn_z,
                                                   const float* __restrict__ epsn_mu,
                                                   const float* __restrict__ logits,
                                                   const float* __restrict__ lse_p,
                                                   float* __restrict__ out) {
    __shared__ float rowbias[64], colbias[64];
    const int tid  = threadIdx.x;
    const int col0 = blockIdx.x * 64;
    const int row0 = blockIdx.y * 64;

    if (tid < 64) {
        const int r = row0 + tid;
        const float4 p0 = *(const float4*)&rn_part[(size_t)r * 8];
        const float4 p1 = *(const float4*)&rn_part[(size_t)r * 8 + 4];
        rowbias[tid] = -0.5f * (p0.x + p0.y + p0.z + p0.w +
                                p1.x + p1.y + p1.z + p1.w + epsn_z[r]);
    } else if (tid < 128) {
        const int c = col0 + tid - 64;
        float v = 0.f;
        if (c < Cn) {
            const float4 p0 = *(const float4*)&cn_part[(size_t)c * 8];
            const float4 p1 = *(const float4*)&cn_part[(size_t)c * 8 + 4];
            v = logits[c] - *lse_p - 0.5f * (p0.x + p0.y + p0.z + p0.w +
                                             p1.x + p1.y + p1.z + p1.w + epsn_mu[c]);
        }
        colbias[tid - 64] = v;
    }

    const int lane = tid & 63, w = tid >> 6;
    const int wr = (w >> 1) * 32, wc = (w & 1) * 32;
    const int la = lane & 15, kg = lane >> 4;

    // A frag: row = la, k = kg*8 + j (contiguous 8 bf16 = 16B)
    const bf16x8* pa = (const bf16x8*)&Yb[(size_t)(row0 + wr + la) * Dn + kg * 8];
    const bf16x8* pb = (const bf16x8*)&Ub[(size_t)(col0 + wc + la) * Dn + kg * 8];
    // units of bf16x8 (8 elems): row stride = 32 units; +16 rows = 512 units

    f32x4 acc00 = {0.f, 0.f, 0.f, 0.f};
    f32x4 acc01 = {0.f, 0.f, 0.f, 0.f};
    f32x4 acc10 = {0.f, 0.f, 0.f, 0.f};
    f32x4 acc11 = {0.f, 0.f, 0.f, 0.f};

#pragma unroll
    for (int kt = 0; kt < 8; ++kt) {
        const bf16x8 a0 = pa[kt * 4];
        const bf16x8 a1 = pa[kt * 4 + 512];
        const bf16x8 b0 = pb[kt * 4];
        const bf16x8 b1 = pb[kt * 4 + 512];
        acc00 = __builtin_amdgcn_mfma_f32_16x16x32_bf16(a0, b0, acc00, 0, 0, 0);
        acc01 = __builtin_amdgcn_mfma_f32_16x16x32_bf16(a0, b1, acc01, 0, 0, 0);
        acc10 = __builtin_amdgcn_mfma_f32_16x16x32_bf16(a1, b0, acc10, 0, 0, 0);
        acc11 = __builtin_amdgcn_mfma_f32_16x16x32_bf16(a1, b1, acc11, 0, 0, 0);
    }
    __syncthreads();

    // C/D layout: col = lane&15, row = (lane>>4)*4 + j   [verified m89]
    const int rbase = kg * 4;
#define EPI(ACC, RF, CF)                                                      \
    do {                                                                      \
        const int gcl = wc + (CF)*16 + la;                                    \
        const int gc  = col0 + gcl;                                           \
        if (gc < Cn) {                                                        \
            const float cb = colbias[gcl];                                    \
            _Pragma("unroll")                                                 \
            for (int j = 0; j < 4; ++j) {                                     \
                const int rl = wr + (RF)*16 + rbase + j;                      \
                out[(size_t)(row0 + rl) * Cn + gc] = ACC[j] + rowbias[rl] + cb; \
            }                                                                 \
        }                                                                     \
    } while (0)

    EPI(acc00, 0, 0); EPI(acc01, 0, 1); EPI(acc10, 1, 0); EPI(acc11, 1, 1);
#undef EPI
}

// ---------------------------------------------------------------------------
extern "C" void kernel_launch(void* const* d_in, const int* in_sizes, int n_in,
                              void* d_out, int out_size, void* d_ws, size_t ws_size,
                              hipStream_t stream) {
    const float* z      = (const float*)d_in[0];   // [1024][256]
    const float* mu     = (const float*)d_in[1];   // [1000][256]
    const float* logits = (const float*)d_in[2];   // [1000]
    const float* F      = (const float*)d_in[3];   // [256][256]
    float* out = (float*)d_out;                    // [1024][1000]

    char* ws = (char*)d_ws;
    unsigned short* Yb = (unsigned short*)(ws);                    // 512 KB [1024][256] bf16
    unsigned short* Ub = (unsigned short*)(ws + (512 << 10));      // 512 KB [1024][256] bf16
    float* rn_part = (float*)(ws + (1 << 20));                     // 32 KB  [1024][8]
    float* cn_part = (float*)(ws + (1 << 20) + (32 << 10));        // 32 KB  [1024][8]
    float* epsn_z  = (float*)(ws + (1 << 20) + (64 << 10));        // 4 KB
    float* epsn_mu = epsn_z + 1024;                                // 4 KB
    float* lse     = epsn_mu + 1024;                               // 4 B

    prep_kernel<<<dim3(257), dim3(256), 0, stream>>>(z, mu, logits, F, Yb, Ub,
                                                     rn_part, cn_part,
                                                     epsn_z, epsn_mu, lse);
    main_kernel<<<dim3(16, 16), dim3(256), 0, stream>>>(Yb, Ub, rn_part, cn_part,
                                                        epsn_z, epsn_mu, logits, lse, out);
}